// Round 8
// baseline (4411.807 us; speedup 1.0000x reference)
//
#include <hip/hip_runtime.h>
#include <hip/hip_bf16.h>

#define NN 100000
#define NE 1600000
#define NG 512
#define NC 10
#define NBINS 782         // 128 dst-nodes per bin
#define BCAP 2560         // per-bin edge cap (mean 2048, ~11 sigma)
#define EPB 8192          // edges per binp1 block

typedef __attribute__((ext_vector_type(8))) short bf16x8;
typedef __attribute__((ext_vector_type(4))) float f32x4;

__device__ __forceinline__ float bflo(unsigned u) { return __uint_as_float(u << 16); }
__device__ __forceinline__ float bfhi(unsigned u) { return __uint_as_float(u & 0xffff0000u); }
__device__ __forceinline__ unsigned short f2bf(float f) {
  unsigned u = __float_as_uint(f);
  unsigned r = u + 0x7fffu + ((u >> 16) & 1u);
  return (unsigned short)(r >> 16);
}

// ---------------- binned CSR build: 128-node bins, 4B records (src<<7|local), src-sorted ----------------

__global__ __launch_bounds__(256) void k_bininit(int* __restrict__ binCursor) {
  int t = blockIdx.x * 256 + threadIdx.x;
  if (t < NBINS) binCursor[t] = t * BCAP;
}

// pass 1: bin-group edges in LDS, burst-write packed records into per-bin stage segments
__global__ __launch_bounds__(256) void k_binp1(const int* __restrict__ src, const int* __restrict__ dst,
                                               int* __restrict__ binCursor, unsigned* __restrict__ stage) {
  __shared__ unsigned srec[EPB];          // 32 KB
  __shared__ unsigned short sbin[EPB];    // 16 KB
  __shared__ int cnt[NBINS], pre[NBINS], base[NBINS], lcur[NBINS];  // 12.5 KB
  __shared__ int tmp[256];
  int t = threadIdx.x;
  for (int i = t; i < NBINS; i += 256) { cnt[i] = 0; lcur[i] = 0; }
  __syncthreads();
  int e0 = blockIdx.x * EPB;
  unsigned myrec[32];
  short mybin[32];
#pragma unroll
  for (int i = 0; i < 32; ++i) {
    int e = e0 + i * 256 + t;
    if (e < NE) {
      int s = src[e], d = dst[e];
      int b = d >> 7;
      mybin[i] = (short)b;
      myrec[i] = ((unsigned)s << 7) | (unsigned)(d & 127);
      atomicAdd(&cnt[b], 1);
    } else mybin[i] = -1;
  }
  __syncthreads();
  // parallel exclusive scan of cnt[782] -> pre[]
  {
    int idx0 = t * 4, s0 = 0, c[4];
#pragma unroll
    for (int k = 0; k < 4; ++k) { int id = idx0 + k; c[k] = (id < NBINS) ? cnt[id] : 0; s0 += c[k]; }
    tmp[t] = s0;
    __syncthreads();
    for (int o = 1; o < 256; o <<= 1) { int v = (t >= o) ? tmp[t - o] : 0; __syncthreads(); tmp[t] += v; __syncthreads(); }
    int ex = tmp[t] - s0;
#pragma unroll
    for (int k = 0; k < 4; ++k) { int id = idx0 + k; if (id < NBINS) pre[id] = ex; ex += c[k]; }
  }
  __syncthreads();
  for (int i = t; i < NBINS; i += 256) if (cnt[i] > 0) base[i] = atomicAdd(&binCursor[i], cnt[i]);
  __syncthreads();
#pragma unroll
  for (int i = 0; i < 32; ++i) {
    int b = mybin[i];
    if (b >= 0) {
      int r = atomicAdd(&lcur[b], 1);
      int pos = pre[b] + r;
      srec[pos] = myrec[i];
      sbin[pos] = (unsigned short)b;
    }
  }
  __syncthreads();
  int total = NE - e0; if (total > EPB) total = EPB;
  for (int sidx = t; sidx < total; sidx += 256) {
    int b = sbin[sidx];
    stage[base[b] + (sidx - pre[b])] = srec[sidx];
  }
}

// pass 2: per bin: deg-histogram -> dinv; counting-sort records by src bucket (src>>7); write csr
__global__ __launch_bounds__(256) void k_binp2(const unsigned* __restrict__ stage, const int* __restrict__ binCursor,
                                               unsigned* __restrict__ csr, float* __restrict__ dinv) {
  __shared__ int ldeg[128];
  __shared__ int bcnt[NBINS], bbase[NBINS];   // 6.3 KB
  __shared__ int tmp[256];
  __shared__ unsigned sorted[BCAP];           // 10 KB
  int b = blockIdx.x, t = threadIdx.x;
  int n0 = b << 7;
  int sbase = b * BCAP;
  int cnt = binCursor[b] - sbase; if (cnt > BCAP) cnt = BCAP;
  for (int i = t; i < NBINS; i += 256) bcnt[i] = 0;
  if (t < 128) ldeg[t] = 0;
  __syncthreads();
  for (int j = t; j < cnt; j += 256) {
    unsigned r = stage[sbase + j];
    atomicAdd(&ldeg[r & 127], 1);
    atomicAdd(&bcnt[r >> 14], 1);   // src bucket = (r>>7)>>7
  }
  __syncthreads();
  if (t < 128) {
    int node = n0 + t;
    if (node < NN) dinv[node] = rsqrtf((float)ldeg[t] + 1.0f);
  }
  // scan bcnt[782] -> bbase (exclusive)
  {
    int idx0 = t * 4, s0 = 0, c[4];
#pragma unroll
    for (int k = 0; k < 4; ++k) { int id = idx0 + k; c[k] = (id < NBINS) ? bcnt[id] : 0; s0 += c[k]; }
    tmp[t] = s0;
    __syncthreads();
    for (int o = 1; o < 256; o <<= 1) { int v = (t >= o) ? tmp[t - o] : 0; __syncthreads(); tmp[t] += v; __syncthreads(); }
    int ex = tmp[t] - s0;
#pragma unroll
    for (int k = 0; k < 4; ++k) { int id = idx0 + k; if (id < NBINS) bbase[id] = ex; ex += c[k]; }
  }
  __syncthreads();
  for (int i = t; i < NBINS; i += 256) bcnt[i] = 0;  // reuse as cursors
  __syncthreads();
  for (int j = t; j < cnt; j += 256) {
    unsigned r = stage[sbase + j];
    int bk = r >> 14;
    int pos = bbase[bk] + atomicAdd(&bcnt[bk], 1);
    sorted[pos] = r;
  }
  __syncthreads();
  for (int j = t; j < cnt; j += 256) csr[sbase + j] = sorted[j];
}

// 4 weight transposes in one launch: Wt[c][k] = bf16(W[k][c])
__global__ __launch_bounds__(256) void k_wt4(const float* __restrict__ Wa, const float* __restrict__ Wb,
                                             const float* __restrict__ Wc, const float* __restrict__ Wd,
                                             unsigned short* __restrict__ Ta, unsigned short* __restrict__ Tb,
                                             unsigned short* __restrict__ Tc, unsigned short* __restrict__ Td) {
  int w = blockIdx.x >> 6;
  const float* W = (w == 0) ? Wa : (w == 1) ? Wb : (w == 2) ? Wc : Wd;
  unsigned short* T = (w == 0) ? Ta : (w == 1) ? Tb : (w == 2) ? Tc : Td;
  int idx = (blockIdx.x & 63) * 256 + threadIdx.x;
  int k = idx >> 7, c = idx & 127;
  T[c * 128 + k] = f2bf(W[k * 128 + c]);
}

// ---------------- bf16 MFMA GEMM: Out[M,128] = (A[M,128] @ W[128,128]) [*dinv_row] ----------------

template<int ADD_BIAS, int RELU, int SRC_F32, int SCALE_ROW>
__global__ __launch_bounds__(256) void k_gemm_mfma(const void* __restrict__ Ap,
                                                   const unsigned short* __restrict__ Wt,
                                                   const float* __restrict__ bias,
                                                   const float* __restrict__ dinv,
                                                   unsigned short* __restrict__ Out, int M) {
  __shared__ uint4 Al4[2048];  // 128 rows x 16 chunks (16B = 8 bf16)
  __shared__ uint4 Wl4[2048];
  int row0 = blockIdx.x * 128;
  const uint4* W16 = (const uint4*)Wt;
#pragma unroll
  for (int it = 0; it < 8; ++it) {
    int idx = it * 256 + threadIdx.x;
    int r = idx >> 4, c = idx & 15;
    int gr = row0 + r;
    uint4 v = make_uint4(0, 0, 0, 0);
    if (gr < M) {
      if (SRC_F32) {
        const float4* Af = (const float4*)Ap;
        float4 f0 = Af[(size_t)gr * 32 + c * 2];
        float4 f1 = Af[(size_t)gr * 32 + c * 2 + 1];
        v.x = (unsigned)f2bf(f0.x) | ((unsigned)f2bf(f0.y) << 16);
        v.y = (unsigned)f2bf(f0.z) | ((unsigned)f2bf(f0.w) << 16);
        v.z = (unsigned)f2bf(f1.x) | ((unsigned)f2bf(f1.y) << 16);
        v.w = (unsigned)f2bf(f1.z) | ((unsigned)f2bf(f1.w) << 16);
      } else {
        v = ((const uint4*)Ap)[(size_t)gr * 16 + c];
      }
    }
    Al4[r * 16 + (c ^ (r & 15))] = v;
    Wl4[r * 16 + (c ^ (r & 15))] = W16[idx];
  }
  __syncthreads();

  int lane = threadIdx.x & 63;
  int wid = threadIdx.x >> 6;
  int wr = wid >> 1, wc = wid & 1;
  int lr = lane & 15, kb = lane >> 4;

  f32x4 acc[4][4] = {};
#pragma unroll
  for (int ks = 0; ks < 4; ++ks) {
    int c = ks * 4 + kb;
    bf16x8 af[4], bfr[4];
#pragma unroll
    for (int i = 0; i < 4; ++i) {
      int ar = wr * 64 + i * 16 + lr;
      af[i] = *(const bf16x8*)&Al4[ar * 16 + (c ^ lr)];
      int bc = wc * 64 + i * 16 + lr;
      bfr[i] = *(const bf16x8*)&Wl4[bc * 16 + (c ^ lr)];
    }
#pragma unroll
    for (int i = 0; i < 4; ++i)
#pragma unroll
      for (int n = 0; n < 4; ++n)
        acc[i][n] = __builtin_amdgcn_mfma_f32_16x16x32_bf16(af[i], bfr[n], acc[i][n], 0, 0, 0);
  }

  float bcol[4];
  if (ADD_BIAS) {
#pragma unroll
    for (int n = 0; n < 4; ++n) bcol[n] = bias[wc * 64 + n * 16 + lr];
  }
#pragma unroll
  for (int i = 0; i < 4; ++i) {
    int rbase = row0 + wr * 64 + i * 16 + kb * 4;
#pragma unroll
    for (int n = 0; n < 4; ++n) {
      int col = wc * 64 + n * 16 + lr;
#pragma unroll
      for (int j = 0; j < 4; ++j) {
        int gr = rbase + j;
        if (gr < M) {
          float v = acc[i][n][j];
          if (ADD_BIAS) v += bcol[n];
          if (RELU) v = fmaxf(v, 0.f);
          if (SCALE_ROW) v *= dinv[gr];
          Out[(size_t)gr * 128 + col] = f2bf(v);
        }
      }
    }
  }
}

// ---------------- edge aggregation v3: dst-block LDS accumulator + src-swept gather ----------------
// Per bin (128 dst nodes): acc[128][128] f32 in LDS (col-permuted: col c<64 = feat 2c, col 64+c = feat 2c+1).
// Each wave processes one edge/iter: full-wave 256B row gather + 2 conflict-free ds_add_f32 per lane.
// Epilogue: out[i] = relu( dinv_i*(acc + hs[i]) + b ).

__global__ __launch_bounds__(256) void k_agg3(const unsigned short* __restrict__ hs,
                                              const unsigned* __restrict__ csr,
                                              const int* __restrict__ binCursor,
                                              const float* __restrict__ dinv,
                                              const float* __restrict__ bias,
                                              unsigned short* __restrict__ out) {
  __shared__ float acc[16384];   // 64 KB
  int b = blockIdx.x, t = threadIdx.x;
  int n0 = b << 7;
  int sbase = b * BCAP;
  int cnt = binCursor[b] - sbase; if (cnt > BCAP) cnt = BCAP;
  for (int i = t; i < 16384; i += 256) acc[i] = 0.f;
  __syncthreads();
  const unsigned* hs32 = (const unsigned*)hs;
  int lane = t & 63, wv = t >> 6;
  for (int cb = wv * 64; cb < cnt; cb += 256) {
    int m = cnt - cb; if (m > 64) m = 64;
    unsigned rec = (cb + lane < cnt) ? csr[sbase + cb + lane] : 0u;
    for (int i = 0; i < m; ++i) {
      unsigned r = __shfl(rec, i);
      unsigned u = hs32[(size_t)(r >> 7) * 64 + lane];
      int local = r & 127;
      atomicAdd(&acc[local * 128 + lane], bflo(u));
      atomicAdd(&acc[local * 128 + 64 + lane], bfhi(u));
    }
  }
  __syncthreads();
  const float2* b2p = (const float2*)bias;
  for (int idx = t; idx < 8192; idx += 256) {
    int r = idx >> 6, c = idx & 63;
    int node = n0 + r;
    if (node < NN) {
      float di = dinv[node];
      unsigned su = hs32[(size_t)node * 64 + c];
      float2 bb = b2p[c];
      float lo = fmaxf(fmaf(acc[r * 128 + c] + bflo(su), di, bb.x), 0.f);
      float hi = fmaxf(fmaf(acc[r * 128 + 64 + c] + bfhi(su), di, bb.y), 0.f);
      ((unsigned*)out)[(size_t)node * 64 + c] = (unsigned)f2bf(lo) | ((unsigned)f2bf(hi) << 16);
    }
  }
}

// ---------------- pooling: 4 row-streams x 64 u32-lanes per graph ----------------

__device__ __forceinline__ int lowerb(const int* a, int n, int key) {
  int lo = 0, hi = n;
  while (lo < hi) {
    int mid = (lo + hi) >> 1;
    if (a[mid] < key) lo = mid + 1; else hi = mid;
  }
  return lo;
}

__global__ __launch_bounds__(256) void k_pool(const unsigned short* __restrict__ h, const int* __restrict__ batch,
                                              float* __restrict__ g) {
  __shared__ float sx[4][64];
  __shared__ float sy[4][64];
  int gi = blockIdx.x;
  int col = threadIdx.x & 63;
  int rp = threadIdx.x >> 6;
  int lo = lowerb(batch, NN, gi), hi = lowerb(batch, NN, gi + 1);
  const unsigned* h32 = (const unsigned*)h;
  float ax = 0.f, ay = 0.f;
  for (int i = lo + rp; i < hi; i += 4) {
    unsigned u = h32[(size_t)i * 64 + col];
    ax += bflo(u);
    ay += bfhi(u);
  }
  sx[rp][col] = ax;
  sy[rp][col] = ay;
  __syncthreads();
  if (rp == 0) {
    ax = sx[0][col] + sx[1][col] + sx[2][col] + sx[3][col];
    ay = sy[0][col] + sy[1][col] + sy[2][col] + sy[3][col];
    ((float2*)g)[gi * 64 + col] = make_float2(ax, ay);
  }
}

// small f32 GEMM for t1 = relu(g @ Wr1 + br1): M=512
__global__ __launch_bounds__(256) void k_gemm_f32(const float* __restrict__ A, const float* __restrict__ W,
                                                  const float* __restrict__ bias, float* __restrict__ Out,
                                                  int M) {
  __shared__ float4 Wl[128 * 32];
  __shared__ float4 Xl[128 * 32];
  const float4* W4 = (const float4*)W;
  for (int i = threadIdx.x; i < 4096; i += 256) Wl[i] = W4[i];
  int row0 = blockIdx.x * 128;
  const float4* A4 = (const float4*)A;
  for (int i = threadIdx.x; i < 4096; i += 256) {
    int r = i >> 5, g = i & 31;
    int gr = row0 + r;
    float4 v = make_float4(0.f, 0.f, 0.f, 0.f);
    if (gr < M) v = A4[gr * 32 + g];
    Xl[r * 32 + (g ^ ((r >> 3) & 7))] = v;
  }
  __syncthreads();

  int cg = threadIdx.x & 15;
  int rg = threadIdx.x >> 4;
  int swz = rg & 7;
  float acc[8][8] = {};
  for (int g = 0; g < 32; ++g) {
    float4 xv[8];
#pragma unroll
    for (int i = 0; i < 8; ++i) xv[i] = Xl[(rg * 8 + i) * 32 + (g ^ swz)];
#pragma unroll
    for (int kk = 0; kk < 4; ++kk) {
      float4 wa = Wl[(g * 4 + kk) * 32 + cg * 2];
      float4 wb = Wl[(g * 4 + kk) * 32 + cg * 2 + 1];
#pragma unroll
      for (int i = 0; i < 8; ++i) {
        float x = (kk == 0) ? xv[i].x : (kk == 1) ? xv[i].y : (kk == 2) ? xv[i].z : xv[i].w;
        acc[i][0] = fmaf(x, wa.x, acc[i][0]);
        acc[i][1] = fmaf(x, wa.y, acc[i][1]);
        acc[i][2] = fmaf(x, wa.z, acc[i][2]);
        acc[i][3] = fmaf(x, wa.w, acc[i][3]);
        acc[i][4] = fmaf(x, wb.x, acc[i][4]);
        acc[i][5] = fmaf(x, wb.y, acc[i][5]);
        acc[i][6] = fmaf(x, wb.z, acc[i][6]);
        acc[i][7] = fmaf(x, wb.w, acc[i][7]);
      }
    }
  }
  float4 ba = ((const float4*)bias)[cg * 2];
  float4 bb = ((const float4*)bias)[cg * 2 + 1];
#pragma unroll
  for (int i = 0; i < 8; ++i) {
    int gr = row0 + rg * 8 + i;
    if (gr < M) {
      float4 oa, ob;
      oa.x = fmaxf(acc[i][0] + ba.x, 0.f); oa.y = fmaxf(acc[i][1] + ba.y, 0.f);
      oa.z = fmaxf(acc[i][2] + ba.z, 0.f); oa.w = fmaxf(acc[i][3] + ba.w, 0.f);
      ob.x = fmaxf(acc[i][4] + bb.x, 0.f); ob.y = fmaxf(acc[i][5] + bb.y, 0.f);
      ob.z = fmaxf(acc[i][6] + bb.z, 0.f); ob.w = fmaxf(acc[i][7] + bb.w, 0.f);
      ((float4*)Out)[gr * 32 + cg * 2] = oa;
      ((float4*)Out)[gr * 32 + cg * 2 + 1] = ob;
    }
  }
}

__global__ __launch_bounds__(128) void k_cls(const float* __restrict__ t, const float* __restrict__ Wr2,
                                             const float* __restrict__ br2, float* __restrict__ out) {
  int gi = blockIdx.x;
  __shared__ float row[128];
  row[threadIdx.x] = t[gi * 128 + threadIdx.x];
  __syncthreads();
  if (threadIdx.x < NC) {
    float acc = br2[threadIdx.x];
    for (int k = 0; k < 128; ++k) acc = fmaf(row[k], Wr2[k * NC + threadIdx.x], acc);
    out[gi * NC + threadIdx.x] = acc;
  }
}

// ---------------- launch ----------------

extern "C" void kernel_launch(void* const* d_in, const int* in_sizes, int n_in,
                              void* d_out, int out_size, void* d_ws, size_t ws_size,
                              hipStream_t stream) {
  const float* x     = (const float*)d_in[0];
  const int*   src   = (const int*)d_in[1];
  const int*   dst   = (const int*)d_in[2];
  const int*   batch = (const int*)d_in[3];
  const float* W_enc = (const float*)d_in[4];
  const float* b_enc = (const float*)d_in[5];
  const float* W1 = (const float*)d_in[6],  *b1 = (const float*)d_in[7];
  const float* W2 = (const float*)d_in[8],  *b2 = (const float*)d_in[9];
  const float* W3 = (const float*)d_in[10], *b3 = (const float*)d_in[11];
  const float* Wr1 = (const float*)d_in[12], *br1 = (const float*)d_in[13];
  const float* Wr2 = (const float*)d_in[14], *br2 = (const float*)d_in[15];
  float* out = (float*)d_out;

  char* ws = (char*)d_ws;
  size_t off = 0;
  auto alloc = [&](size_t bytes) {
    void* p = ws + off;
    off = (off + bytes + 255) & ~(size_t)255;
    return p;
  };
  unsigned short* h   = (unsigned short*)alloc((size_t)NN * 128 * 2);
  unsigned short* hs  = (unsigned short*)alloc((size_t)NN * 128 * 2);
  unsigned short* WtE = (unsigned short*)alloc(128 * 128 * 2);
  unsigned short* Wt1 = (unsigned short*)alloc(128 * 128 * 2);
  unsigned short* Wt2 = (unsigned short*)alloc(128 * 128 * 2);
  unsigned short* Wt3 = (unsigned short*)alloc(128 * 128 * 2);
  float* dinv     = (float*)alloc((size_t)NN * 4);
  int*   binCursor= (int*)alloc(NBINS * 4);
  unsigned* csr   = (unsigned*)alloc((size_t)NBINS * BCAP * 4);
  unsigned* stage = (unsigned*)alloc((size_t)NBINS * BCAP * 4);
  float* g        = (float*)alloc((size_t)NG * 128 * 4);
  float* t1       = (float*)alloc((size_t)NG * 128 * 4);

  k_bininit<<<4, 256, 0, stream>>>(binCursor);
  k_binp1<<<(NE + EPB - 1) / EPB, 256, 0, stream>>>(src, dst, binCursor, stage);
  k_binp2<<<NBINS, 256, 0, stream>>>(stage, binCursor, csr, dinv);

  k_wt4<<<256, 256, 0, stream>>>(W_enc, W1, W2, W3, WtE, Wt1, Wt2, Wt3);

  int gM = (NN + 127) / 128;  // 782
  k_gemm_mfma<1, 0, 1, 0><<<gM, 256, 0, stream>>>(x, WtE, b_enc, nullptr, h, NN);

  const unsigned short* Wts[3] = {Wt1, Wt2, Wt3};
  const float* bs[3] = {b1, b2, b3};
  for (int L = 0; L < 3; ++L) {
    k_gemm_mfma<0, 0, 0, 1><<<gM, 256, 0, stream>>>(h, Wts[L], nullptr, dinv, hs, NN);
    k_agg3<<<NBINS, 256, 0, stream>>>(hs, csr, binCursor, dinv, bs[L], h);
  }

  k_pool<<<NG, 256, 0, stream>>>(h, batch, g);
  k_gemm_f32<<<(NG + 127) / 128, 256, 0, stream>>>(g, Wr1, br1, t1, NG);
  k_cls<<<NG, 128, 0, stream>>>(t1, Wr2, br2, out);
}

// Round 9
// 437.894 us; speedup vs baseline: 10.0751x; 10.0751x over previous
//
#include <hip/hip_runtime.h>
#include <hip/hip_bf16.h>

#define NN 100000
#define NE 1600000
#define NG 512
#define NC 10
#define NBINS 196         // 512 dst-nodes per bin
#define BINCAP 10240      // per-bin edge cap (mean 8192, ~22 sigma)
#define EPB 8192          // edges per binp1 block

typedef __attribute__((ext_vector_type(8))) short bf16x8;
typedef __attribute__((ext_vector_type(4))) float f32x4;
typedef int int4a __attribute__((ext_vector_type(4), aligned(4)));

__device__ __forceinline__ float bflo(unsigned u) { return __uint_as_float(u << 16); }
__device__ __forceinline__ float bfhi(unsigned u) { return __uint_as_float(u & 0xffff0000u); }
__device__ __forceinline__ unsigned short f2bf(float f) {
  unsigned u = __float_as_uint(f);
  unsigned r = u + 0x7fffu + ((u >> 16) & 1u);
  return (unsigned short)(r >> 16);
}

// ---------------- binned CSR build: 512-node bins, 4B records (src<<9|local), src-sorted lists ----------------

__global__ __launch_bounds__(256) void k_bininit(int* __restrict__ binCursor) {
  int t = threadIdx.x;
  if (t < NBINS) binCursor[t] = t * BINCAP;
}

// pass 1: bin-group edges in LDS, burst-write packed records into per-bin stage segments
__global__ __launch_bounds__(256) void k_binp1(const int* __restrict__ src, const int* __restrict__ dst,
                                               int* __restrict__ binCursor, unsigned* __restrict__ stage) {
  __shared__ unsigned srec[EPB];          // 32 KB
  __shared__ unsigned char sbin[EPB];     // 8 KB
  __shared__ int cnt[NBINS], pre[NBINS], base[NBINS], lcur[NBINS];
  __shared__ int tmp[256];
  int t = threadIdx.x;
  if (t < NBINS) { cnt[t] = 0; lcur[t] = 0; }
  __syncthreads();
  int e0 = blockIdx.x * EPB;
  unsigned myrec[32];
  short mybin[32];
#pragma unroll
  for (int i = 0; i < 32; ++i) {
    int e = e0 + i * 256 + t;
    if (e < NE) {
      int s = src[e], d = dst[e];
      int b = d >> 9;
      mybin[i] = (short)b;
      myrec[i] = ((unsigned)s << 9) | (unsigned)(d & 511);
      atomicAdd(&cnt[b], 1);
    } else mybin[i] = -1;
  }
  __syncthreads();
  // exclusive scan cnt[196] -> pre
  int c0 = (t < NBINS) ? cnt[t] : 0;
  tmp[t] = c0;
  __syncthreads();
  for (int o = 1; o < 256; o <<= 1) { int v = (t >= o) ? tmp[t - o] : 0; __syncthreads(); tmp[t] += v; __syncthreads(); }
  if (t < NBINS) pre[t] = tmp[t] - c0;
  __syncthreads();
  if (t < NBINS && c0 > 0) base[t] = atomicAdd(&binCursor[t], c0);
  __syncthreads();
#pragma unroll
  for (int i = 0; i < 32; ++i) {
    int b = mybin[i];
    if (b >= 0) {
      int r = atomicAdd(&lcur[b], 1);
      int pos = pre[b] + r;
      srec[pos] = myrec[i];
      sbin[pos] = (unsigned char)b;
    }
  }
  __syncthreads();
  int total = NE - e0; if (total > EPB) total = EPB;
  for (int sidx = t; sidx < total; sidx += 256) {
    int b = sbin[sidx];
    stage[base[b] + (sidx - pre[b])] = srec[sidx];
  }
}

// pass 2: per bin: deg histogram -> offs/deg/dinv; counting-sort by src bucket; scatter per-node
// lists in src-sorted order (L2 sweep banding for agg)
__global__ __launch_bounds__(256) void k_binp2(const unsigned* __restrict__ stage, const int* __restrict__ binCursor,
                                               int* __restrict__ csr_src, int* __restrict__ offs,
                                               int* __restrict__ deg, float* __restrict__ dinv) {
  __shared__ int ldeg[512], loff[512], lcur[512];
  __shared__ int sbc[NBINS], sbb[NBINS];
  __shared__ int tmp[256];
  __shared__ unsigned sorted[BINCAP];     // 40 KB
  int b = blockIdx.x, t = threadIdx.x;
  int n0 = b << 9;
  int sbase = b * BINCAP;
  int cnt = binCursor[b] - sbase; if (cnt > BINCAP) cnt = BINCAP;
  for (int i = t; i < 512; i += 256) { ldeg[i] = 0; lcur[i] = 0; }
  if (t < NBINS) sbc[t] = 0;
  __syncthreads();
  for (int j = t; j < cnt; j += 256) {
    unsigned r = stage[sbase + j];
    atomicAdd(&ldeg[r & 511], 1);
    atomicAdd(&sbc[r >> 18], 1);     // src bucket = src>>9
  }
  __syncthreads();
  // scan ldeg[512] (2 per thread) -> loff; emit offs/deg/dinv
  int i2 = t * 2;
  int a0 = ldeg[i2], a1 = ldeg[i2 + 1];
  int s = a0 + a1;
  tmp[t] = s;
  __syncthreads();
  for (int o = 1; o < 256; o <<= 1) { int v = (t >= o) ? tmp[t - o] : 0; __syncthreads(); tmp[t] += v; __syncthreads(); }
  int ex = tmp[t] - s;
  loff[i2] = ex;
  loff[i2 + 1] = ex + a0;
  int nd0 = n0 + i2, nd1 = n0 + i2 + 1;
  if (nd0 < NN) { offs[nd0] = sbase + ex;      deg[nd0] = a0; dinv[nd0] = rsqrtf((float)a0 + 1.0f); }
  if (nd1 < NN) { offs[nd1] = sbase + ex + a0; deg[nd1] = a1; dinv[nd1] = rsqrtf((float)a1 + 1.0f); }
  __syncthreads();
  // scan sbc[196] -> sbb
  int c0 = (t < NBINS) ? sbc[t] : 0;
  tmp[t] = c0;
  __syncthreads();
  for (int o = 1; o < 256; o <<= 1) { int v = (t >= o) ? tmp[t - o] : 0; __syncthreads(); tmp[t] += v; __syncthreads(); }
  if (t < NBINS) { sbb[t] = tmp[t] - c0; sbc[t] = 0; }   // sbc reused as cursor
  __syncthreads();
  // counting sort records by src bucket
  for (int j = t; j < cnt; j += 256) {
    unsigned r = stage[sbase + j];
    int bk = r >> 18;
    sorted[sbb[bk] + atomicAdd(&sbc[bk], 1)] = r;
  }
  __syncthreads();
  // scatter in src-sorted order -> per-node lists come out src-banded
  for (int j = t; j < cnt; j += 256) {
    unsigned r = sorted[j];
    int li = r & 511;
    int pos = atomicAdd(&lcur[li], 1);
    csr_src[sbase + loff[li] + pos] = (int)(r >> 9);
  }
}

// 4 weight transposes in one launch: Wt[c][k] = bf16(W[k][c])
__global__ __launch_bounds__(256) void k_wt4(const float* __restrict__ Wa, const float* __restrict__ Wb,
                                             const float* __restrict__ Wc, const float* __restrict__ Wd,
                                             unsigned short* __restrict__ Ta, unsigned short* __restrict__ Tb,
                                             unsigned short* __restrict__ Tc, unsigned short* __restrict__ Td) {
  int w = blockIdx.x >> 6;
  const float* W = (w == 0) ? Wa : (w == 1) ? Wb : (w == 2) ? Wc : Wd;
  unsigned short* T = (w == 0) ? Ta : (w == 1) ? Tb : (w == 2) ? Tc : Td;
  int idx = (blockIdx.x & 63) * 256 + threadIdx.x;
  int k = idx >> 7, c = idx & 127;
  T[c * 128 + k] = f2bf(W[k * 128 + c]);
}

// ---------------- bf16 MFMA GEMM: Out[M,128] = (A[M,128] @ W[128,128]) [*dinv_row] ----------------

template<int ADD_BIAS, int RELU, int SRC_F32, int SCALE_ROW>
__global__ __launch_bounds__(256) void k_gemm_mfma(const void* __restrict__ Ap,
                                                   const unsigned short* __restrict__ Wt,
                                                   const float* __restrict__ bias,
                                                   const float* __restrict__ dinv,
                                                   unsigned short* __restrict__ Out, int M) {
  __shared__ uint4 Al4[2048];  // 128 rows x 16 chunks (16B = 8 bf16)
  __shared__ uint4 Wl4[2048];
  int row0 = blockIdx.x * 128;
  const uint4* W16 = (const uint4*)Wt;
#pragma unroll
  for (int it = 0; it < 8; ++it) {
    int idx = it * 256 + threadIdx.x;
    int r = idx >> 4, c = idx & 15;
    int gr = row0 + r;
    uint4 v = make_uint4(0, 0, 0, 0);
    if (gr < M) {
      if (SRC_F32) {
        const float4* Af = (const float4*)Ap;
        float4 f0 = Af[(size_t)gr * 32 + c * 2];
        float4 f1 = Af[(size_t)gr * 32 + c * 2 + 1];
        v.x = (unsigned)f2bf(f0.x) | ((unsigned)f2bf(f0.y) << 16);
        v.y = (unsigned)f2bf(f0.z) | ((unsigned)f2bf(f0.w) << 16);
        v.z = (unsigned)f2bf(f1.x) | ((unsigned)f2bf(f1.y) << 16);
        v.w = (unsigned)f2bf(f1.z) | ((unsigned)f2bf(f1.w) << 16);
      } else {
        v = ((const uint4*)Ap)[(size_t)gr * 16 + c];
      }
    }
    Al4[r * 16 + (c ^ (r & 15))] = v;
    Wl4[r * 16 + (c ^ (r & 15))] = W16[idx];
  }
  __syncthreads();

  int lane = threadIdx.x & 63;
  int wid = threadIdx.x >> 6;
  int wr = wid >> 1, wc = wid & 1;
  int lr = lane & 15, kb = lane >> 4;

  f32x4 acc[4][4] = {};
#pragma unroll
  for (int ks = 0; ks < 4; ++ks) {
    int c = ks * 4 + kb;
    bf16x8 af[4], bfr[4];
#pragma unroll
    for (int i = 0; i < 4; ++i) {
      int ar = wr * 64 + i * 16 + lr;
      af[i] = *(const bf16x8*)&Al4[ar * 16 + (c ^ lr)];
      int bc = wc * 64 + i * 16 + lr;
      bfr[i] = *(const bf16x8*)&Wl4[bc * 16 + (c ^ lr)];
    }
#pragma unroll
    for (int i = 0; i < 4; ++i)
#pragma unroll
      for (int n = 0; n < 4; ++n)
        acc[i][n] = __builtin_amdgcn_mfma_f32_16x16x32_bf16(af[i], bfr[n], acc[i][n], 0, 0, 0);
  }

  float bcol[4];
  if (ADD_BIAS) {
#pragma unroll
    for (int n = 0; n < 4; ++n) bcol[n] = bias[wc * 64 + n * 16 + lr];
  }
#pragma unroll
  for (int i = 0; i < 4; ++i) {
    int rbase = row0 + wr * 64 + i * 16 + kb * 4;
#pragma unroll
    for (int n = 0; n < 4; ++n) {
      int col = wc * 64 + n * 16 + lr;
#pragma unroll
      for (int j = 0; j < 4; ++j) {
        int gr = rbase + j;
        if (gr < M) {
          float v = acc[i][n][j];
          if (ADD_BIAS) v += bcol[n];
          if (RELU) v = fmaxf(v, 0.f);
          if (SCALE_ROW) v *= dinv[gr];
          Out[(size_t)gr * 128 + col] = f2bf(v);
        }
      }
    }
  }
}

// ---------------- edge aggregation: wave/node, 16 gathers in flight (round-7 structure) ----------------
// hs = (h@W) * dinv (from GEMM).  out[i] = relu( (sum_e hs[src] + hs[i]) * dinv_i + b )

__global__ __launch_bounds__(256) void k_agg(const unsigned short* __restrict__ hs,
                                             const int* __restrict__ offs, const int* __restrict__ deg,
                                             const float* __restrict__ dinv,
                                             const int* __restrict__ csr_src,
                                             const float* __restrict__ bias,
                                             unsigned short* __restrict__ out) {
  int node = blockIdx.x * 4 + (threadIdx.x >> 6);
  if (node >= NN) return;
  int l = threadIdx.x & 63;
  const unsigned* hs32 = (const unsigned*)hs;  // 64 u32 per row
  float di = dinv[node];
  unsigned v = hs32[(size_t)node * 64 + l];
  float ax = bflo(v), ay = bfhi(v);  // self term hs[i]
  int p0 = offs[node], n = deg[node];
  int p = 0;
  for (; p + 16 <= n; p += 16) {
    const int* cp = csr_src + p0 + p;
    int4a i0 = *(const int4a*)cp;
    int4a i1 = *(const int4a*)(cp + 4);
    int4a i2 = *(const int4a*)(cp + 8);
    int4a i3 = *(const int4a*)(cp + 12);
    unsigned u0  = hs32[(size_t)i0.x * 64 + l], u1  = hs32[(size_t)i0.y * 64 + l];
    unsigned u2  = hs32[(size_t)i0.z * 64 + l], u3  = hs32[(size_t)i0.w * 64 + l];
    unsigned u4  = hs32[(size_t)i1.x * 64 + l], u5  = hs32[(size_t)i1.y * 64 + l];
    unsigned u6  = hs32[(size_t)i1.z * 64 + l], u7  = hs32[(size_t)i1.w * 64 + l];
    unsigned u8  = hs32[(size_t)i2.x * 64 + l], u9  = hs32[(size_t)i2.y * 64 + l];
    unsigned u10 = hs32[(size_t)i2.z * 64 + l], u11 = hs32[(size_t)i2.w * 64 + l];
    unsigned u12 = hs32[(size_t)i3.x * 64 + l], u13 = hs32[(size_t)i3.y * 64 + l];
    unsigned u14 = hs32[(size_t)i3.z * 64 + l], u15 = hs32[(size_t)i3.w * 64 + l];
    ax += bflo(u0) + bflo(u1) + bflo(u2) + bflo(u3) + bflo(u4) + bflo(u5) + bflo(u6) + bflo(u7)
        + bflo(u8) + bflo(u9) + bflo(u10) + bflo(u11) + bflo(u12) + bflo(u13) + bflo(u14) + bflo(u15);
    ay += bfhi(u0) + bfhi(u1) + bfhi(u2) + bfhi(u3) + bfhi(u4) + bfhi(u5) + bfhi(u6) + bfhi(u7)
        + bfhi(u8) + bfhi(u9) + bfhi(u10) + bfhi(u11) + bfhi(u12) + bfhi(u13) + bfhi(u14) + bfhi(u15);
  }
  for (; p + 8 <= n; p += 8) {
    const int* cp = csr_src + p0 + p;
    int4a i0 = *(const int4a*)cp;
    int4a i1 = *(const int4a*)(cp + 4);
    unsigned u0 = hs32[(size_t)i0.x * 64 + l], u1 = hs32[(size_t)i0.y * 64 + l];
    unsigned u2 = hs32[(size_t)i0.z * 64 + l], u3 = hs32[(size_t)i0.w * 64 + l];
    unsigned u4 = hs32[(size_t)i1.x * 64 + l], u5 = hs32[(size_t)i1.y * 64 + l];
    unsigned u6 = hs32[(size_t)i1.z * 64 + l], u7 = hs32[(size_t)i1.w * 64 + l];
    ax += bflo(u0) + bflo(u1) + bflo(u2) + bflo(u3) + bflo(u4) + bflo(u5) + bflo(u6) + bflo(u7);
    ay += bfhi(u0) + bfhi(u1) + bfhi(u2) + bfhi(u3) + bfhi(u4) + bfhi(u5) + bfhi(u6) + bfhi(u7);
  }
  for (; p < n; ++p) {
    int s0 = csr_src[p0 + p];
    unsigned u0 = hs32[(size_t)s0 * 64 + l];
    ax += bflo(u0);
    ay += bfhi(u0);
  }
  float2 b2 = ((const float2*)bias)[l];
  ax = fmaxf(fmaf(ax, di, b2.x), 0.f);
  ay = fmaxf(fmaf(ay, di, b2.y), 0.f);
  ((unsigned*)out)[(size_t)node * 64 + l] = (unsigned)f2bf(ax) | ((unsigned)f2bf(ay) << 16);
}

// ---------------- pooling: 4 row-streams x 64 u32-lanes per graph ----------------

__device__ __forceinline__ int lowerb(const int* a, int n, int key) {
  int lo = 0, hi = n;
  while (lo < hi) {
    int mid = (lo + hi) >> 1;
    if (a[mid] < key) lo = mid + 1; else hi = mid;
  }
  return lo;
}

__global__ __launch_bounds__(256) void k_pool(const unsigned short* __restrict__ h, const int* __restrict__ batch,
                                              float* __restrict__ g) {
  __shared__ float sx[4][64];
  __shared__ float sy[4][64];
  int gi = blockIdx.x;
  int col = threadIdx.x & 63;
  int rp = threadIdx.x >> 6;
  int lo = lowerb(batch, NN, gi), hi = lowerb(batch, NN, gi + 1);
  const unsigned* h32 = (const unsigned*)h;
  float ax = 0.f, ay = 0.f;
  for (int i = lo + rp; i < hi; i += 4) {
    unsigned u = h32[(size_t)i * 64 + col];
    ax += bflo(u);
    ay += bfhi(u);
  }
  sx[rp][col] = ax;
  sy[rp][col] = ay;
  __syncthreads();
  if (rp == 0) {
    ax = sx[0][col] + sx[1][col] + sx[2][col] + sx[3][col];
    ay = sy[0][col] + sy[1][col] + sy[2][col] + sy[3][col];
    ((float2*)g)[gi * 64 + col] = make_float2(ax, ay);
  }
}

// small f32 GEMM for t1 = relu(g @ Wr1 + br1): M=512
__global__ __launch_bounds__(256) void k_gemm_f32(const float* __restrict__ A, const float* __restrict__ W,
                                                  const float* __restrict__ bias, float* __restrict__ Out,
                                                  int M) {
  __shared__ float4 Wl[128 * 32];
  __shared__ float4 Xl[128 * 32];
  const float4* W4 = (const float4*)W;
  for (int i = threadIdx.x; i < 4096; i += 256) Wl[i] = W4[i];
  int row0 = blockIdx.x * 128;
  const float4* A4 = (const float4*)A;
  for (int i = threadIdx.x; i < 4096; i += 256) {
    int r = i >> 5, g = i & 31;
    int gr = row0 + r;
    float4 v = make_float4(0.f, 0.f, 0.f, 0.f);
    if (gr < M) v = A4[gr * 32 + g];
    Xl[r * 32 + (g ^ ((r >> 3) & 7))] = v;
  }
  __syncthreads();

  int cg = threadIdx.x & 15;
  int rg = threadIdx.x >> 4;
  int swz = rg & 7;
  float acc[8][8] = {};
  for (int g = 0; g < 32; ++g) {
    float4 xv[8];
#pragma unroll
    for (int i = 0; i < 8; ++i) xv[i] = Xl[(rg * 8 + i) * 32 + (g ^ swz)];
#pragma unroll
    for (int kk = 0; kk < 4; ++kk) {
      float4 wa = Wl[(g * 4 + kk) * 32 + cg * 2];
      float4 wb = Wl[(g * 4 + kk) * 32 + cg * 2 + 1];
#pragma unroll
      for (int i = 0; i < 8; ++i) {
        float x = (kk == 0) ? xv[i].x : (kk == 1) ? xv[i].y : (kk == 2) ? xv[i].z : xv[i].w;
        acc[i][0] = fmaf(x, wa.x, acc[i][0]);
        acc[i][1] = fmaf(x, wa.y, acc[i][1]);
        acc[i][2] = fmaf(x, wa.z, acc[i][2]);
        acc[i][3] = fmaf(x, wa.w, acc[i][3]);
        acc[i][4] = fmaf(x, wb.x, acc[i][4]);
        acc[i][5] = fmaf(x, wb.y, acc[i][5]);
        acc[i][6] = fmaf(x, wb.z, acc[i][6]);
        acc[i][7] = fmaf(x, wb.w, acc[i][7]);
      }
    }
  }
  float4 ba = ((const float4*)bias)[cg * 2];
  float4 bb = ((const float4*)bias)[cg * 2 + 1];
#pragma unroll
  for (int i = 0; i < 8; ++i) {
    int gr = row0 + rg * 8 + i;
    if (gr < M) {
      float4 oa, ob;
      oa.x = fmaxf(acc[i][0] + ba.x, 0.f); oa.y = fmaxf(acc[i][1] + ba.y, 0.f);
      oa.z = fmaxf(acc[i][2] + ba.z, 0.f); oa.w = fmaxf(acc[i][3] + ba.w, 0.f);
      ob.x = fmaxf(acc[i][4] + bb.x, 0.f); ob.y = fmaxf(acc[i][5] + bb.y, 0.f);
      ob.z = fmaxf(acc[i][6] + bb.z, 0.f); ob.w = fmaxf(acc[i][7] + bb.w, 0.f);
      ((float4*)Out)[gr * 32 + cg * 2] = oa;
      ((float4*)Out)[gr * 32 + cg * 2 + 1] = ob;
    }
  }
}

__global__ __launch_bounds__(128) void k_cls(const float* __restrict__ t, const float* __restrict__ Wr2,
                                             const float* __restrict__ br2, float* __restrict__ out) {
  int gi = blockIdx.x;
  __shared__ float row[128];
  row[threadIdx.x] = t[gi * 128 + threadIdx.x];
  __syncthreads();
  if (threadIdx.x < NC) {
    float acc = br2[threadIdx.x];
    for (int k = 0; k < 128; ++k) acc = fmaf(row[k], Wr2[k * NC + threadIdx.x], acc);
    out[gi * NC + threadIdx.x] = acc;
  }
}

// ---------------- launch ----------------

extern "C" void kernel_launch(void* const* d_in, const int* in_sizes, int n_in,
                              void* d_out, int out_size, void* d_ws, size_t ws_size,
                              hipStream_t stream) {
  const float* x     = (const float*)d_in[0];
  const int*   src   = (const int*)d_in[1];
  const int*   dst   = (const int*)d_in[2];
  const int*   batch = (const int*)d_in[3];
  const float* W_enc = (const float*)d_in[4];
  const float* b_enc = (const float*)d_in[5];
  const float* W1 = (const float*)d_in[6],  *b1 = (const float*)d_in[7];
  const float* W2 = (const float*)d_in[8],  *b2 = (const float*)d_in[9];
  const float* W3 = (const float*)d_in[10], *b3 = (const float*)d_in[11];
  const float* Wr1 = (const float*)d_in[12], *br1 = (const float*)d_in[13];
  const float* Wr2 = (const float*)d_in[14], *br2 = (const float*)d_in[15];
  float* out = (float*)d_out;

  char* ws = (char*)d_ws;
  size_t off = 0;
  auto alloc = [&](size_t bytes) {
    void* p = ws + off;
    off = (off + bytes + 255) & ~(size_t)255;
    return p;
  };
  unsigned short* h   = (unsigned short*)alloc((size_t)NN * 128 * 2);
  unsigned short* hs  = (unsigned short*)alloc((size_t)NN * 128 * 2);
  unsigned short* WtE = (unsigned short*)alloc(128 * 128 * 2);
  unsigned short* Wt1 = (unsigned short*)alloc(128 * 128 * 2);
  unsigned short* Wt2 = (unsigned short*)alloc(128 * 128 * 2);
  unsigned short* Wt3 = (unsigned short*)alloc(128 * 128 * 2);
  int*   deg      = (int*)alloc((size_t)NN * 4);
  float* dinv     = (float*)alloc((size_t)NN * 4);
  int*   offs     = (int*)alloc((size_t)NN * 4);
  int*   binCursor= (int*)alloc(NBINS * 4);
  int*   csr_src  = (int*)alloc((size_t)NBINS * BINCAP * 4);
  unsigned* stage = (unsigned*)alloc((size_t)NBINS * BINCAP * 4);
  float* g        = (float*)alloc((size_t)NG * 128 * 4);
  float* t1       = (float*)alloc((size_t)NG * 128 * 4);

  k_bininit<<<1, 256, 0, stream>>>(binCursor);
  k_binp1<<<(NE + EPB - 1) / EPB, 256, 0, stream>>>(src, dst, binCursor, stage);
  k_binp2<<<NBINS, 256, 0, stream>>>(stage, binCursor, csr_src, offs, deg, dinv);

  k_wt4<<<256, 256, 0, stream>>>(W_enc, W1, W2, W3, WtE, Wt1, Wt2, Wt3);

  int gM = (NN + 127) / 128;  // 782
  k_gemm_mfma<1, 0, 1, 0><<<gM, 256, 0, stream>>>(x, WtE, b_enc, nullptr, h, NN);

  const unsigned short* Wts[3] = {Wt1, Wt2, Wt3};
  const float* bs[3] = {b1, b2, b3};
  int gA = (NN + 3) / 4;  // 25000
  for (int L = 0; L < 3; ++L) {
    k_gemm_mfma<0, 0, 0, 1><<<gM, 256, 0, stream>>>(h, Wts[L], nullptr, dinv, hs, NN);
    k_agg<<<gA, 256, 0, stream>>>(hs, offs, deg, dinv, csr_src, bs[L], h);
  }

  k_pool<<<NG, 256, 0, stream>>>(h, batch, g);
  k_gemm_f32<<<(NG + 127) / 128, 256, 0, stream>>>(g, Wr1, br1, t1, NG);
  k_cls<<<NG, 128, 0, stream>>>(t1, Wr2, br2, out);
}